// Round 4
// baseline (45022.711 us; speedup 1.0000x reference)
//
#include <hip/hip_runtime.h>
#include <hip/hip_cooperative_groups.h>

namespace cg = cooperative_groups;

#define S_ELE (256 * 1024)   // one [B=256, H=1024] plane (floats)

__device__ __forceinline__ float clip01(float b) { return fminf(fmaxf(b, 0.0f), 1.0f); }

// ---- 64x64 tile of C = A(64xK) * B^T(64xK), K = KCH*16. 64 threads, 8x8/thread.
// Single-buffered k-major LDS (8704 B), register prefetch. Per-output-element
// accumulation strictly sequential in k (bitwise identical to round-2 gemm64). ----
template <int KCH>
__device__ __forceinline__ void gemm64_sb(float* __restrict__ sm,
    const float* __restrict__ A, long lda,
    const float* __restrict__ B, long ldb,
    float* __restrict__ Pout, int tm, int tn)
{
    float* As = sm;            // [16][68]
    float* Bs = sm + 1088;     // [16][68]
    const int lane = (int)threadIdx.x;
    const int sr = lane >> 2;           // 0..15
    const int sk = (lane & 3) << 2;     // 0,4,8,12
    const int r0 = (lane >> 3) << 3;    // 8-row group
    const int cq = (lane & 7) << 2;     // 4-col group (+32)

    const float* Ab = A + (size_t)(tm * 64) * lda;
    const float* Bb = B + (size_t)(tn * 64) * ldb;

    float4 pa[4], pb[4];
    #pragma unroll
    for (int p = 0; p < 4; ++p) {
        pa[p] = *reinterpret_cast<const float4*>(&Ab[(size_t)(sr + 16 * p) * lda + sk]);
        pb[p] = *reinterpret_cast<const float4*>(&Bb[(size_t)(sr + 16 * p) * ldb + sk]);
    }

    float acc[8][8] = {};

    #pragma unroll 2
    for (int c = 0; c < KCH; ++c) {
        __syncthreads();                 // 1-wave block: near-free
        #pragma unroll
        for (int p = 0; p < 4; ++p) {
            const int m = sr + 16 * p;
            As[(sk + 0) * 68 + m] = pa[p].x; As[(sk + 1) * 68 + m] = pa[p].y;
            As[(sk + 2) * 68 + m] = pa[p].z; As[(sk + 3) * 68 + m] = pa[p].w;
            Bs[(sk + 0) * 68 + m] = pb[p].x; Bs[(sk + 1) * 68 + m] = pb[p].y;
            Bs[(sk + 2) * 68 + m] = pb[p].z; Bs[(sk + 3) * 68 + m] = pb[p].w;
        }
        __syncthreads();
        if (c + 1 < KCH) {               // prefetch next chunk under the FMAs
            const int ko = (c + 1) * 16;
            #pragma unroll
            for (int p = 0; p < 4; ++p) {
                pa[p] = *reinterpret_cast<const float4*>(&Ab[(size_t)(sr + 16 * p) * lda + ko + sk]);
                pb[p] = *reinterpret_cast<const float4*>(&Bb[(size_t)(sr + 16 * p) * ldb + ko + sk]);
            }
        }
        #pragma unroll
        for (int k = 0; k < 16; ++k) {
            float4 a0 = *reinterpret_cast<const float4*>(&As[k * 68 + r0]);
            float4 a1 = *reinterpret_cast<const float4*>(&As[k * 68 + r0 + 4]);
            float4 b0 = *reinterpret_cast<const float4*>(&Bs[k * 68 + cq]);
            float4 b1 = *reinterpret_cast<const float4*>(&Bs[k * 68 + cq + 32]);
            float a[8] = {a0.x, a0.y, a0.z, a0.w, a1.x, a1.y, a1.z, a1.w};
            float b[8] = {b0.x, b0.y, b0.z, b0.w, b1.x, b1.y, b1.z, b1.w};
            #pragma unroll
            for (int i = 0; i < 8; ++i)
                #pragma unroll
                for (int j = 0; j < 8; ++j)
                    acc[i][j] = fmaf(a[i], b[j], acc[i][j]);
        }
    }

    #pragma unroll
    for (int i = 0; i < 8; ++i) {
        float4 v0 = make_float4(acc[i][0], acc[i][1], acc[i][2], acc[i][3]);
        float4 v1 = make_float4(acc[i][4], acc[i][5], acc[i][6], acc[i][7]);
        float* row = Pout + (size_t)(tm * 64 + r0 + i) * 1024 + tn * 64;
        *reinterpret_cast<float4*>(&row[cq])      = v0;
        *reinterpret_cast<float4*>(&row[cq + 32]) = v1;
    }
}

// ---- phase-A task dispatch: 832 wave-tasks over 1024 blocks ----
__device__ __forceinline__ void phaseA_task(float* sm, int bid, int tau,
    const float* x, const float* W1, const float* W1r,
    const float* W2, const float* W2r,
    const float* spk1, const float* spk2, float* P1, float* P2)
{
    if (bid < 512) {                     // spk1 @ W1r^T, 8-split K=128 -> P1 planes 1..8
        if (tau < 100) {
            const int sp = bid >> 6, tile = bid & 63;
            gemm64_sb<8>(sm, spk1 + (size_t)sp * 128, 1024,
                         W1r + (size_t)sp * 128, 1024,
                         P1 + (size_t)(1 + sp) * S_ELE, tile & 3, tile >> 2);
        }
    } else if (bid < 576) {              // x_tau @ W1^T, full K=512 -> P1 plane 0
        if (tau < 100) {
            const int tile = bid - 512;
            gemm64_sb<32>(sm, x + (size_t)tau * 512, 51200, W1, 512,
                          P1, tile & 3, tile >> 2);
        }
    } else if (bid < 832) {              // layer-2 partials for step tau-1 (round-2 order)
        if (tau >= 1) {
            const int t2 = bid - 576;
            const int plane = t2 >> 6, tile = t2 & 63;   // plane = pair*2 + split
            const int p = plane >> 1, s = plane & 1;
            const float* Am = p ? spk2 : spk1;
            const float* Bm = p ? W2r  : W2;
            gemm64_sb<32>(sm, Am + (size_t)s * 512, 1024, Bm + (size_t)s * 512, 1024,
                          P2 + (size_t)plane * S_ELE, tile & 3, tile >> 2);
        }
    }
}

// ---- update layer 1: cur = xw + P1..P8 sequential (round-2 validated order) ----
__device__ __forceinline__ void upd1_slice(int slice, int lane, const float* P1,
    const float* b1p, float* mem1, float* spk1, float* rec_t)
{
    const float b = clip01(*b1p);
    const int i = (slice * 64 + lane) * 4;
    float4 cur = *reinterpret_cast<const float4*>(&P1[i]);
    #pragma unroll
    for (int sp = 0; sp < 8; ++sp) {
        float4 p = *reinterpret_cast<const float4*>(&P1[(size_t)(1 + sp) * S_ELE + i]);
        cur.x += p.x; cur.y += p.y; cur.z += p.z; cur.w += p.w;
    }
    float4 mo = *reinterpret_cast<const float4*>(&mem1[i]);
    float4 mn, sv;
    mn.x = b * mo.x + cur.x - (mo.x > 1.0f ? 1.0f : 0.0f); sv.x = (mn.x - 1.0f) > 0.0f ? 1.0f : 0.0f;
    mn.y = b * mo.y + cur.y - (mo.y > 1.0f ? 1.0f : 0.0f); sv.y = (mn.y - 1.0f) > 0.0f ? 1.0f : 0.0f;
    mn.z = b * mo.z + cur.z - (mo.z > 1.0f ? 1.0f : 0.0f); sv.z = (mn.z - 1.0f) > 0.0f ? 1.0f : 0.0f;
    mn.w = b * mo.w + cur.w - (mo.w > 1.0f ? 1.0f : 0.0f); sv.w = (mn.w - 1.0f) > 0.0f ? 1.0f : 0.0f;
    *reinterpret_cast<float4*>(&mem1[i])  = mn;
    *reinterpret_cast<float4*>(&spk1[i])  = sv;
    *reinterpret_cast<float4*>(&rec_t[i]) = sv;
}

// ---- update layer 2 + fused readout: cur2 = (P0+P1)+(P2+P3) (round-2 order) ----
__device__ __forceinline__ void l2ro_row(float* sm, int bb, int lane, const float* P2,
    const float* b2p, const float* bop, float* mem2, float* spk2,
    const float* Wout, float* memo, float* rec_t)
{
    const float b  = clip01(*b2p);
    const float bo = clip01(*bop);
    #pragma unroll
    for (int j = 0; j < 4; ++j) {
        const int e = j * 256 + lane * 4;
        const size_t base = (size_t)bb * 1024 + e;
        float4 p0 = *reinterpret_cast<const float4*>(&P2[base]);
        float4 p1 = *reinterpret_cast<const float4*>(&P2[(size_t)S_ELE + base]);
        float4 p2 = *reinterpret_cast<const float4*>(&P2[(size_t)2 * S_ELE + base]);
        float4 p3 = *reinterpret_cast<const float4*>(&P2[(size_t)3 * S_ELE + base]);
        float4 cur;
        cur.x = (p0.x + p1.x) + (p2.x + p3.x);
        cur.y = (p0.y + p1.y) + (p2.y + p3.y);
        cur.z = (p0.z + p1.z) + (p2.z + p3.z);
        cur.w = (p0.w + p1.w) + (p2.w + p3.w);
        float4 mo = *reinterpret_cast<const float4*>(&mem2[base]);
        float4 mn, sv;
        mn.x = b * mo.x + cur.x - (mo.x > 1.0f ? 1.0f : 0.0f); sv.x = (mn.x - 1.0f) > 0.0f ? 1.0f : 0.0f;
        mn.y = b * mo.y + cur.y - (mo.y > 1.0f ? 1.0f : 0.0f); sv.y = (mn.y - 1.0f) > 0.0f ? 1.0f : 0.0f;
        mn.z = b * mo.z + cur.z - (mo.z > 1.0f ? 1.0f : 0.0f); sv.z = (mn.z - 1.0f) > 0.0f ? 1.0f : 0.0f;
        mn.w = b * mo.w + cur.w - (mo.w > 1.0f ? 1.0f : 0.0f); sv.w = (mn.w - 1.0f) > 0.0f ? 1.0f : 0.0f;
        *reinterpret_cast<float4*>(&mem2[base]) = mn;
        *reinterpret_cast<float4*>(&spk2[base]) = sv;
        *reinterpret_cast<float4*>(&sm[e])      = sv;
    }
    __syncthreads();
    float v[16];
    #pragma unroll
    for (int i = 0; i < 16; ++i) v[i] = sm[lane + 64 * i];
    for (int o = 0; o < 10; ++o) {
        float sum = 0.0f;
        #pragma unroll
        for (int i = 0; i < 16; ++i)
            sum = fmaf(v[i], Wout[o * 1024 + lane + 64 * i], sum);
        #pragma unroll
        for (int off = 32; off > 0; off >>= 1) sum += __shfl_down(sum, off);
        if (lane == 0) {
            const float m = bo * memo[bb * 10 + o] + sum;
            memo[bb * 10 + o] = m;
            rec_t[bb * 10 + o] = m;
        }
    }
}

// ---- persistent cooperative kernel: whole 100-step loop, 2 grid syncs/step ----
// grid = 1024 blocks x 64 threads, 8704 B LDS/block (safe even under a 64KB/CU
// occupancy model: 7 blocks/CU -> coop max 1792 >= 1024).
__global__ __launch_bounds__(64, 2) void snn_all(
    const float* __restrict__ x,   const float* __restrict__ W1,
    const float* __restrict__ W1r, const float* __restrict__ W2,
    const float* __restrict__ W2r, const float* __restrict__ Wout,
    const float* __restrict__ b1p, const float* __restrict__ b2p,
    const float* __restrict__ bop,
    float* __restrict__ spk1_rec, float* __restrict__ mout_rec,
    float* __restrict__ mem1, float* __restrict__ mem2,
    float* __restrict__ spk1, float* __restrict__ spk2,
    float* __restrict__ P1, float* __restrict__ P2, float* __restrict__ memo)
{
    cg::grid_group grid = cg::this_grid();
    __shared__ float sm[2176];          // 8704 B
    const int bid  = (int)blockIdx.x;
    const int lane = (int)threadIdx.x;

    for (int tau = 0; tau <= 100; ++tau) {
        phaseA_task(sm, bid, tau, x, W1, W1r, W2, W2r, spk1, spk2, P1, P2);
        grid.sync();
        if (tau < 100)
            upd1_slice(bid, lane, P1, b1p, mem1, spk1,
                       spk1_rec + (size_t)tau * S_ELE);
        if (tau >= 1 && bid < 256)
            l2ro_row(sm, bid, lane, P2, b2p, bop, mem2, spk2, Wout, memo,
                     mout_rec + (size_t)(tau - 1) * 2560);
        grid.sync();
    }
}

// ---- fallback (non-cooperative) kernels: 4 launches/step, same device code ----
__global__ __launch_bounds__(64, 2) void fb_phaseA_l1(const float* __restrict__ x_t,
    const float* __restrict__ W1, const float* __restrict__ spk1,
    const float* __restrict__ W1r, float* __restrict__ P1)
{
    __shared__ float sm[2176];
    const int bid = (int)blockIdx.x;    // 0..575
    if (bid < 512) {
        const int sp = bid >> 6, tile = bid & 63;
        gemm64_sb<8>(sm, spk1 + (size_t)sp * 128, 1024, W1r + (size_t)sp * 128, 1024,
                     P1 + (size_t)(1 + sp) * S_ELE, tile & 3, tile >> 2);
    } else {
        const int tile = bid - 512;
        gemm64_sb<32>(sm, x_t, 51200, W1, 512, P1, tile & 3, tile >> 2);
    }
}

__global__ __launch_bounds__(64) void fb_upd1(const float* __restrict__ P1,
    const float* __restrict__ b1p, float* __restrict__ mem1,
    float* __restrict__ spk1, float* __restrict__ rec_t)
{
    upd1_slice((int)blockIdx.x, (int)threadIdx.x, P1, b1p, mem1, spk1, rec_t);
}

__global__ __launch_bounds__(64, 2) void fb_phaseA_l2(const float* __restrict__ spk1,
    const float* __restrict__ spk2, const float* __restrict__ W2,
    const float* __restrict__ W2r, float* __restrict__ P2)
{
    __shared__ float sm[2176];
    const int bid = (int)blockIdx.x;    // 0..255
    const int plane = bid >> 6, tile = bid & 63;
    const int p = plane >> 1, s = plane & 1;
    const float* Am = p ? spk2 : spk1;
    const float* Bm = p ? W2r  : W2;
    gemm64_sb<32>(sm, Am + (size_t)s * 512, 1024, Bm + (size_t)s * 512, 1024,
                  P2 + (size_t)plane * S_ELE, tile & 3, tile >> 2);
}

__global__ __launch_bounds__(64) void fb_l2ro(const float* __restrict__ P2,
    const float* __restrict__ b2p, const float* __restrict__ bop,
    float* __restrict__ mem2, float* __restrict__ spk2,
    const float* __restrict__ Wout, float* __restrict__ memo,
    float* __restrict__ rec_t)
{
    __shared__ float sm[1024];
    l2ro_row(sm, (int)blockIdx.x, (int)threadIdx.x, P2, b2p, bop,
             mem2, spk2, Wout, memo, rec_t);
}

extern "C" void kernel_launch(void* const* d_in, const int* in_sizes, int n_in,
                              void* d_out, int out_size, void* d_ws, size_t ws_size,
                              hipStream_t stream)
{
    const float* x    = (const float*)d_in[0];   // [256,100,512]
    const float* W1   = (const float*)d_in[1];   // [1024,512]
    const float* W1r  = (const float*)d_in[2];   // [1024,1024]
    const float* W2   = (const float*)d_in[3];   // [1024,1024]
    const float* W2r  = (const float*)d_in[4];   // [1024,1024]
    const float* Wout = (const float*)d_in[5];   // [10,1024]
    const float* b1   = (const float*)d_in[6];
    const float* b2   = (const float*)d_in[7];
    const float* bo   = (const float*)d_in[8];

    float* out      = (float*)d_out;
    float* spk1_rec = out;                         // [100,256,1024]
    float* mout_rec = out + (size_t)100 * S_ELE;   // [100,256,10]

    float* w = (float*)d_ws;
    float* mem1 = w;  w += S_ELE;
    float* mem2 = w;  w += S_ELE;
    float* spk1 = w;  w += S_ELE;
    float* spk2 = w;  w += S_ELE;
    float* P1   = w;  w += 9 * S_ELE;    // plane 0: xw; planes 1..8: recurrent splits
    float* P2   = w;  w += 4 * S_ELE;    // W2 lo/hi, W2r lo/hi
    float* memo = w;  w += 2560;

    hipMemsetAsync(mem1, 0, (size_t)S_ELE * 4, stream);
    hipMemsetAsync(mem2, 0, (size_t)S_ELE * 4, stream);
    hipMemsetAsync(spk1, 0, (size_t)S_ELE * 4, stream);
    hipMemsetAsync(spk2, 0, (size_t)S_ELE * 4, stream);
    hipMemsetAsync(memo, 0, 2560 * 4, stream);

    int maxb = 0;
    hipError_t qerr = hipOccupancyMaxActiveBlocksPerMultiprocessor(
        &maxb, (const void*)snn_all, 64, 0);
    bool coop = (qerr == hipSuccess && maxb >= 4);

    if (coop) {
        void* args[] = {
            (void*)&x, (void*)&W1, (void*)&W1r, (void*)&W2, (void*)&W2r, (void*)&Wout,
            (void*)&b1, (void*)&b2, (void*)&bo,
            (void*)&spk1_rec, (void*)&mout_rec,
            (void*)&mem1, (void*)&mem2, (void*)&spk1, (void*)&spk2,
            (void*)&P1, (void*)&P2, (void*)&memo
        };
        if (hipLaunchCooperativeKernel((const void*)snn_all, dim3(1024), dim3(64),
                                       args, 0, stream) != hipSuccess)
            coop = false;
    }

    if (!coop) {
        for (int t = 0; t < 100; ++t) {
            hipLaunchKernelGGL(fb_phaseA_l1, dim3(576), dim3(64), 0, stream,
                               x + (size_t)t * 512, W1, spk1, W1r, P1);
            hipLaunchKernelGGL(fb_upd1, dim3(1024), dim3(64), 0, stream,
                               P1, b1, mem1, spk1, spk1_rec + (size_t)t * S_ELE);
            hipLaunchKernelGGL(fb_phaseA_l2, dim3(256), dim3(64), 0, stream,
                               spk1, spk2, W2, W2r, P2);
            hipLaunchKernelGGL(fb_l2ro, dim3(256), dim3(64), 0, stream,
                               P2, b2, bo, mem2, spk2, Wout, memo,
                               mout_rec + (size_t)t * 2560);
        }
    }
}

// Round 5
// 5690.927 us; speedup vs baseline: 7.9113x; 7.9113x over previous
//
#include <hip/hip_runtime.h>

#define S_ELE (256 * 1024)   // one [B=256, H=1024] plane (floats)
#define NBLK 512

struct Ptrs {
    const float *x, *W1, *W1r, *W2, *W2r, *Wout;
    const float *b1, *b2, *bo;
    float *spk1_rec, *mout_rec;
    float *mem1, *mem2, *memo;
    float *w1rt, *w2t, *w2rt, *xw;
    unsigned *bar, *cnt1, *cnt2;
    unsigned short *idx1, *idx2;
    int t_ch;
};

__device__ __forceinline__ float clip01(float b) { return fminf(fmaxf(b, 0.0f), 1.0f); }
__device__ __forceinline__ float4 ld4(const float* p) { return *reinterpret_cast<const float4*>(p); }
__device__ __forceinline__ void   st4(float* p, float4 v) { *reinterpret_cast<float4*>(p) = v; }

// validated membrane update (round-2 arithmetic)
__device__ __forceinline__ float4 memup(float4 mo, float4 cur, float b, float4* sv)
{
    float4 mn, s;
    mn.x = b * mo.x + cur.x - (mo.x > 1.0f ? 1.0f : 0.0f); s.x = (mn.x - 1.0f) > 0.0f ? 1.0f : 0.0f;
    mn.y = b * mo.y + cur.y - (mo.y > 1.0f ? 1.0f : 0.0f); s.y = (mn.y - 1.0f) > 0.0f ? 1.0f : 0.0f;
    mn.z = b * mo.z + cur.z - (mo.z > 1.0f ? 1.0f : 0.0f); s.z = (mn.z - 1.0f) > 0.0f ? 1.0f : 0.0f;
    mn.w = b * mo.w + cur.w - (mo.w > 1.0f ? 1.0f : 0.0f); s.w = (mn.w - 1.0f) > 0.0f ? 1.0f : 0.0f;
    *sv = s; return mn;
}

// two-level grid barrier: 8 group counters (64 blocks each) -> top counter -> gen
__device__ __forceinline__ void gbar(unsigned* bar)
{
    __syncthreads();
    if (threadIdx.x == 0) {
        unsigned g = __hip_atomic_load(&bar[0], __ATOMIC_RELAXED, __HIP_MEMORY_SCOPE_AGENT);
        unsigned* gc = &bar[8 + (blockIdx.x & 7) * 32];
        unsigned a = __hip_atomic_fetch_add(gc, 1u, __ATOMIC_ACQ_REL, __HIP_MEMORY_SCOPE_AGENT);
        if (a == (NBLK / 8) - 1) {
            __hip_atomic_store(gc, 0u, __ATOMIC_RELAXED, __HIP_MEMORY_SCOPE_AGENT);
            unsigned tp = __hip_atomic_fetch_add(&bar[1], 1u, __ATOMIC_ACQ_REL, __HIP_MEMORY_SCOPE_AGENT);
            if (tp == 7u) {
                __hip_atomic_store(&bar[1], 0u, __ATOMIC_RELAXED, __HIP_MEMORY_SCOPE_AGENT);
                __hip_atomic_store(&bar[0], g + 1u, __ATOMIC_RELEASE, __HIP_MEMORY_SCOPE_AGENT);
            }
        }
        while (__hip_atomic_load(&bar[0], __ATOMIC_ACQUIRE, __HIP_MEMORY_SCOPE_AGENT) == g)
            __builtin_amdgcn_s_sleep(2);
    }
    __syncthreads();
}

// 32x32 transpose tile: dst[k][n] = src[n][k]
__device__ __forceinline__ void tr32(float* sm, const float* src, float* dst, int tr, int tc)
{
    const int t = (int)threadIdx.x;
    const int r = t >> 3, c4 = (t & 7) << 2;
    __syncthreads();
    float4 v = ld4(src + (size_t)(tr * 32 + r) * 1024 + tc * 32 + c4);
    sm[r * 33 + c4 + 0] = v.x; sm[r * 33 + c4 + 1] = v.y;
    sm[r * 33 + c4 + 2] = v.z; sm[r * 33 + c4 + 3] = v.w;
    __syncthreads();
    const int kk = t >> 3, nn4 = (t & 7) << 2;
    float4 o;
    o.x = sm[(nn4 + 0) * 33 + kk]; o.y = sm[(nn4 + 1) * 33 + kk];
    o.z = sm[(nn4 + 2) * 33 + kk]; o.w = sm[(nn4 + 3) * 33 + kk];
    st4(dst + (size_t)(tc * 32 + kk) * 1024 + tr * 32 + nn4, o);
}

// dense 128x128 tile of x_t @ W1^T, K=512, 256 thr, 8x8/thread, k-ascending fmaf chain
__device__ __forceinline__ void xw_tile(float* sm, const float* xA, const float* W1,
                                        float* out, int tm, int tn)
{
    float* As = sm;            // [16][132]
    float* Bs = sm + 2112;     // [16][132]
    const int t = (int)threadIdx.x;
    const int ar = t >> 1;             // 0..127
    const int ak = (t & 1) << 3;       // 0 or 8
    const int r0 = (t >> 4) << 3;
    const int c0 = (t & 15) << 3;
    const float* Ab = xA + (size_t)(tm * 128) * 51200;
    const float* Bb = W1 + (size_t)(tn * 128) * 512;
    float4 pa0 = ld4(Ab + (size_t)ar * 51200 + ak);
    float4 pa1 = ld4(Ab + (size_t)ar * 51200 + ak + 4);
    float4 pb0 = ld4(Bb + (size_t)ar * 512 + ak);
    float4 pb1 = ld4(Bb + (size_t)ar * 512 + ak + 4);
    float acc[8][8] = {};
    for (int c = 0; c < 32; ++c) {
        __syncthreads();
        As[(ak + 0) * 132 + ar] = pa0.x; As[(ak + 1) * 132 + ar] = pa0.y;
        As[(ak + 2) * 132 + ar] = pa0.z; As[(ak + 3) * 132 + ar] = pa0.w;
        As[(ak + 4) * 132 + ar] = pa1.x; As[(ak + 5) * 132 + ar] = pa1.y;
        As[(ak + 6) * 132 + ar] = pa1.z; As[(ak + 7) * 132 + ar] = pa1.w;
        Bs[(ak + 0) * 132 + ar] = pb0.x; Bs[(ak + 1) * 132 + ar] = pb0.y;
        Bs[(ak + 2) * 132 + ar] = pb0.z; Bs[(ak + 3) * 132 + ar] = pb0.w;
        Bs[(ak + 4) * 132 + ar] = pb1.x; Bs[(ak + 5) * 132 + ar] = pb1.y;
        Bs[(ak + 6) * 132 + ar] = pb1.z; Bs[(ak + 7) * 132 + ar] = pb1.w;
        __syncthreads();
        if (c + 1 < 32) {
            const int ko = (c + 1) * 16;
            pa0 = ld4(Ab + (size_t)ar * 51200 + ko + ak);
            pa1 = ld4(Ab + (size_t)ar * 51200 + ko + ak + 4);
            pb0 = ld4(Bb + (size_t)ar * 512 + ko + ak);
            pb1 = ld4(Bb + (size_t)ar * 512 + ko + ak + 4);
        }
        #pragma unroll
        for (int k = 0; k < 16; ++k) {
            float4 a0 = ld4(&As[k * 132 + r0]);
            float4 a1 = ld4(&As[k * 132 + r0 + 4]);
            float4 b0 = ld4(&Bs[k * 132 + c0]);
            float4 b1 = ld4(&Bs[k * 132 + c0 + 4]);
            float av[8] = {a0.x, a0.y, a0.z, a0.w, a1.x, a1.y, a1.z, a1.w};
            float bv[8] = {b0.x, b0.y, b0.z, b0.w, b1.x, b1.y, b1.z, b1.w};
            #pragma unroll
            for (int i = 0; i < 8; ++i)
                #pragma unroll
                for (int j = 0; j < 8; ++j)
                    acc[i][j] = fmaf(av[i], bv[j], acc[i][j]);
        }
    }
    #pragma unroll
    for (int i = 0; i < 8; ++i) {
        float* row = out + (size_t)(tm * 128 + r0 + i) * 1024 + tn * 128 + c0;
        st4(row,     make_float4(acc[i][0], acc[i][1], acc[i][2], acc[i][3]));
        st4(row + 4, make_float4(acc[i][4], acc[i][5], acc[i][6], acc[i][7]));
    }
}

// two independent k-ordered sparse chains (1-deep prefetch each); bitwise = dense chain
__device__ __forceinline__ void sp_pair(const unsigned short* lst,
    unsigned j0, unsigned e0, unsigned j1, unsigned e1,
    const float* Wt, int n4, float4& r0, float4& r1)
{
    float4 a = {0, 0, 0, 0}, b = {0, 0, 0, 0};
    float4 va, vb;
    if (j0 < e0) va = ld4(Wt + (size_t)lst[j0] * 1024 + n4);
    if (j1 < e1) vb = ld4(Wt + (size_t)lst[j1] * 1024 + n4);
    while (j0 < e0 || j1 < e1) {
        if (j0 < e0) {
            float4 v = va; unsigned jn = j0 + 1;
            if (jn < e0) va = ld4(Wt + (size_t)lst[jn] * 1024 + n4);
            a.x += v.x; a.y += v.y; a.z += v.z; a.w += v.w;
            j0 = jn;
        }
        if (j1 < e1) {
            float4 v = vb; unsigned jn = j1 + 1;
            if (jn < e1) vb = ld4(Wt + (size_t)lst[jn] * 1024 + n4);
            b.x += v.x; b.y += v.y; b.z += v.z; b.w += v.w;
            j1 = jn;
        }
    }
    r0 = a; r1 = b;
}

// wave-0 compaction: sorted nonzero indices + per-128-window counts
__device__ __forceinline__ void build_list(const float* s_spk,
    unsigned short* gidx, unsigned* gcnt)
{
    const int l = (int)threadIdx.x;   // 0..63
    unsigned tot = 0, prev = 0;
    #pragma unroll
    for (int i = 0; i < 16; ++i) {
        float s = s_spk[i * 64 + l];
        unsigned long long m = __ballot(s != 0.0f);
        unsigned off = (unsigned)__popcll(m & ((1ull << l) - 1ull));
        if (s != 0.0f) gidx[tot + off] = (unsigned short)(i * 64 + l);
        tot += (unsigned)__popcll(m);
        if (i & 1) { if (l == 0) gcnt[i >> 1] = tot - prev; prev = tot; }
    }
}

// layer-1 row: cur = xw + P1..P8 (sparse, validated order); update; build new list
__device__ __forceinline__ void l1_row(float* sm, const Ptrs& p, int b, int tau)
{
    const int t = (int)threadIdx.x;
    const int n4 = t << 2;
    const int pp = 1 - (tau & 1), cp = tau & 1;
    const unsigned* cw = p.cnt1 + ((size_t)pp * 256 + b) * 8;
    unsigned pos[9];
    pos[0] = 0;
    #pragma unroll
    for (int w = 0; w < 8; ++w) pos[w + 1] = pos[w] + cw[w];
    const unsigned tot = pos[8];
    unsigned* sl = (unsigned*)(sm + 1024);
    const unsigned* gl = (const unsigned*)(p.idx1 + ((size_t)pp * 256 + b) * 1024);
    for (unsigned i = t; i < ((tot + 1) >> 1); i += 256) sl[i] = gl[i];
    __syncthreads();
    const unsigned short* sl16 = (const unsigned short*)sl;

    const int slot = tau % p.t_ch;
    float4 acc = ld4(p.xw + (size_t)slot * S_ELE + (size_t)b * 1024 + n4);
    #pragma unroll
    for (int w = 0; w < 8; w += 2) {
        float4 pa, pb;
        sp_pair(sl16, pos[w], pos[w + 1], pos[w + 1], pos[w + 2], p.w1rt, n4, pa, pb);
        acc.x += pa.x; acc.y += pa.y; acc.z += pa.z; acc.w += pa.w;
        acc.x += pb.x; acc.y += pb.y; acc.z += pb.z; acc.w += pb.w;
    }
    const float bb = clip01(*p.b1);
    float4 mo = ld4(p.mem1 + (size_t)b * 1024 + n4);
    float4 sv; float4 mn = memup(mo, acc, bb, &sv);
    st4(p.mem1 + (size_t)b * 1024 + n4, mn);
    st4(p.spk1_rec + (size_t)tau * S_ELE + (size_t)b * 1024 + n4, sv);
    sm[n4 + 0] = sv.x; sm[n4 + 1] = sv.y; sm[n4 + 2] = sv.z; sm[n4 + 3] = sv.w;
    __syncthreads();
    if (t < 64) build_list(sm, p.idx1 + ((size_t)cp * 256 + b) * 1024,
                           p.cnt1 + ((size_t)cp * 256 + b) * 8);
}

// layer-2 row for step s: cur2 = (P0+P1)+(P2+P3) (sparse, validated order);
// update + spk2-list build + fused readout (round-2 readout arithmetic)
__device__ __forceinline__ void l2_row(float* sm, const Ptrs& p, int b, int step)
{
    const int t = (int)threadIdx.x;
    const int n4 = t << 2;
    const int p1par = step & 1;          // list1(step)
    const int p2par = 1 - (step & 1);    // list2(step-1)
    const unsigned* c1 = p.cnt1 + ((size_t)p1par * 256 + b) * 8;
    const unsigned* c2 = p.cnt2 + ((size_t)p2par * 256 + b) * 8;
    unsigned nlo1 = c1[0] + c1[1] + c1[2] + c1[3];
    unsigned tot1 = nlo1 + c1[4] + c1[5] + c1[6] + c1[7];
    unsigned nlo2 = c2[0] + c2[1] + c2[2] + c2[3];
    unsigned tot2 = nlo2 + c2[4] + c2[5] + c2[6] + c2[7];
    unsigned* sl1 = (unsigned*)(sm + 1024);
    unsigned* sl2 = (unsigned*)(sm + 1536);
    const unsigned* g1 = (const unsigned*)(p.idx1 + ((size_t)p1par * 256 + b) * 1024);
    const unsigned* g2 = (const unsigned*)(p.idx2 + ((size_t)p2par * 256 + b) * 1024);
    for (unsigned i = t; i < ((tot1 + 1) >> 1); i += 256) sl1[i] = g1[i];
    for (unsigned i = t; i < ((tot2 + 1) >> 1); i += 256) sl2[i] = g2[i];
    __syncthreads();

    float4 plo, phi, prlo, prhi;
    sp_pair((const unsigned short*)sl1, 0, nlo1, nlo1, tot1, p.w2t,  n4, plo, phi);
    sp_pair((const unsigned short*)sl2, 0, nlo2, nlo2, tot2, p.w2rt, n4, prlo, prhi);
    float4 cur;
    cur.x = (plo.x + phi.x) + (prlo.x + prhi.x);
    cur.y = (plo.y + phi.y) + (prlo.y + prhi.y);
    cur.z = (plo.z + phi.z) + (prlo.z + prhi.z);
    cur.w = (plo.w + phi.w) + (prlo.w + prhi.w);

    const float bb = clip01(*p.b2);
    float4 mo = ld4(p.mem2 + (size_t)b * 1024 + n4);
    float4 sv; float4 mn = memup(mo, cur, bb, &sv);
    st4(p.mem2 + (size_t)b * 1024 + n4, mn);
    sm[n4 + 0] = sv.x; sm[n4 + 1] = sv.y; sm[n4 + 2] = sv.z; sm[n4 + 3] = sv.w;
    __syncthreads();
    if (t < 64) build_list(sm, p.idx2 + ((size_t)(step & 1) * 256 + b) * 1024,
                           p.cnt2 + ((size_t)(step & 1) * 256 + b) * 8);
    // readout (round-2 validated)
    const int wave = t >> 6, lane = t & 63;
    const float bo = clip01(*p.bo);
    float v[16];
    #pragma unroll
    for (int i = 0; i < 16; ++i) v[i] = sm[lane + 64 * i];
    float* rec = p.mout_rec + (size_t)step * 2560;
    for (int o = wave; o < 10; o += 4) {
        float sum = 0.0f;
        #pragma unroll
        for (int i = 0; i < 16; ++i)
            sum = fmaf(v[i], p.Wout[o * 1024 + lane + 64 * i], sum);
        #pragma unroll
        for (int off = 32; off > 0; off >>= 1) sum += __shfl_down(sum, off);
        if (lane == 0) {
            const float m = bo * p.memo[b * 10 + o] + sum;
            p.memo[b * 10 + o] = m;
            rec[b * 10 + o] = m;
        }
    }
}

// ---- persistent cooperative kernel: 1 barrier/step ----
__global__ __launch_bounds__(256, 2) void snn_all(Ptrs p)
{
    __shared__ float sm[4224];
    const int bid = (int)blockIdx.x;

    // pre: transpose W1r, W2, W2r into [k][n]
    for (int task = bid; task < 3072; task += NBLK) {
        const float* src = task < 1024 ? p.W1r : (task < 2048 ? p.W2 : p.W2r);
        float* dst = task < 1024 ? p.w1rt : (task < 2048 ? p.w2t : p.w2rt);
        const int id = task & 1023;
        tr32(sm, src, dst, id >> 5, id & 31);
    }
    gbar(p.bar);

    for (int tau = 0; tau <= 100; ++tau) {
        if (tau < 100 && (tau % p.t_ch) == 0) {
            const int ntask = p.t_ch * 16;
            for (int task = bid; task < ntask; task += NBLK) {
                const int tp = task >> 4, tile = task & 15;
                xw_tile(sm, p.x + (size_t)(tau + tp) * 512, p.W1,
                        p.xw + (size_t)tp * S_ELE, tile >> 3, tile & 7);
            }
            gbar(p.bar);
        }
        if (bid < 256) { if (tau < 100) l1_row(sm, p, bid, tau); }
        else           { if (tau >= 1)  l2_row(sm, p, bid - 256, tau - 1); }
        gbar(p.bar);
    }
}

// ---- fallback kernels (same device code, kernel boundaries as barriers) ----
__global__ __launch_bounds__(256, 2) void fb_pre(Ptrs p)
{
    __shared__ float sm[4224];
    for (int task = blockIdx.x; task < 3072; task += gridDim.x) {
        const float* src = task < 1024 ? p.W1r : (task < 2048 ? p.W2 : p.W2r);
        float* dst = task < 1024 ? p.w1rt : (task < 2048 ? p.w2t : p.w2rt);
        const int id = task & 1023;
        tr32(sm, src, dst, id >> 5, id & 31);
    }
}

__global__ __launch_bounds__(256, 2) void fb_xw(Ptrs p, int t0)
{
    __shared__ float sm[4224];
    const int task = (int)blockIdx.x;
    const int tp = task >> 4, tile = task & 15;
    xw_tile(sm, p.x + (size_t)(t0 + tp) * 512, p.W1,
            p.xw + (size_t)tp * S_ELE, tile >> 3, tile & 7);
}

__global__ __launch_bounds__(256, 2) void fb_iter(Ptrs p, int tau)
{
    __shared__ float sm[4224];
    const int bid = (int)blockIdx.x;
    if (bid < 256) { if (tau < 100) l1_row(sm, p, bid, tau); }
    else           { if (tau >= 1)  l2_row(sm, p, bid - 256, tau - 1); }
}

extern "C" void kernel_launch(void* const* d_in, const int* in_sizes, int n_in,
                              void* d_out, int out_size, void* d_ws, size_t ws_size,
                              hipStream_t stream)
{
    Ptrs p;
    p.x    = (const float*)d_in[0];
    p.W1   = (const float*)d_in[1];
    p.W1r  = (const float*)d_in[2];
    p.W2   = (const float*)d_in[3];
    p.W2r  = (const float*)d_in[4];
    p.Wout = (const float*)d_in[5];
    p.b1   = (const float*)d_in[6];
    p.b2   = (const float*)d_in[7];
    p.bo   = (const float*)d_in[8];

    float* out = (float*)d_out;
    p.spk1_rec = out;
    p.mout_rec = out + (size_t)100 * S_ELE;

    float* w = (float*)d_ws;
    p.mem1 = w;  w += S_ELE;
    p.mem2 = w;  w += S_ELE;
    p.memo = w;  w += 2560;
    p.bar  = (unsigned*)w;  w += 512;
    p.cnt1 = (unsigned*)w;  w += 4096;
    p.cnt2 = (unsigned*)w;  w += 4096;
    p.idx1 = (unsigned short*)w;  w += 262144;   // 2 x 256 x 1024 u16 = 1 MB
    p.idx2 = (unsigned short*)w;  w += 262144;
    p.w1rt = w;  w += 1048576;
    p.w2t  = w;  w += 1048576;
    p.w2rt = w;  w += 1048576;
    p.xw   = w;

    const size_t used = (size_t)(w - (float*)d_ws) * sizeof(float);
    int t_ch = 1;
    const int cands[] = {100, 50, 25, 20, 10, 5, 4, 2, 1};
    for (int c : cands)
        if (used + (size_t)c * S_ELE * sizeof(float) <= ws_size) { t_ch = c; break; }
    p.t_ch = t_ch;

    // zero mem1..cnt2 (contiguous) — also resets barrier state for graph replays
    hipMemsetAsync(p.mem1, 0,
                   ((size_t)2 * S_ELE + 2560 + 512 + 8192) * sizeof(float), stream);

    int maxb = 0;
    hipError_t qerr = hipOccupancyMaxActiveBlocksPerMultiprocessor(
        &maxb, (const void*)snn_all, 256, 0);
    bool coop = (qerr == hipSuccess && maxb >= 2);

    if (coop) {
        void* args[] = { (void*)&p };
        if (hipLaunchCooperativeKernel((const void*)snn_all, dim3(NBLK), dim3(256),
                                       args, 0, stream) != hipSuccess)
            coop = false;
    }

    if (!coop) {
        hipLaunchKernelGGL(fb_pre, dim3(NBLK), dim3(256), 0, stream, p);
        for (int tau = 0; tau <= 100; ++tau) {
            if (tau < 100 && (tau % t_ch) == 0)
                hipLaunchKernelGGL(fb_xw, dim3(t_ch * 16), dim3(256), 0, stream, p, tau);
            hipLaunchKernelGGL(fb_iter, dim3(NBLK), dim3(256), 0, stream, p, tau);
        }
    }
}

// Round 6
// 5272.276 us; speedup vs baseline: 8.5395x; 1.0794x over previous
//
#include <hip/hip_runtime.h>

#define S_ELE (256 * 1024)   // one [B=256, H=1024] plane (floats)
#define NBLK 1024
#define GRP  8
#define GSZ  (NBLK / GRP)

struct Ptrs {
    const float *x, *W1, *W1r, *W2, *W2r, *Wout;
    const float *b1, *b2, *bo;
    float *spk1_rec, *mout_rec;
    float *mem1, *mem2, *memo;
    float *w1rt, *w2t, *w2rt, *xw, *P1, *P2;
    unsigned *bar, *cnt1, *cnt2;
    unsigned short *idx1, *idx2;
    int t_ch;
};

__device__ __forceinline__ float clip01(float b) { return fminf(fmaxf(b, 0.0f), 1.0f); }
__device__ __forceinline__ float4 ld4(const float* p) { return *reinterpret_cast<const float4*>(p); }
__device__ __forceinline__ void   st4(float* p, float4 v) { *reinterpret_cast<float4*>(p) = v; }

// validated membrane update (round-2 arithmetic)
__device__ __forceinline__ float4 memup(float4 mo, float4 cur, float b, float4* sv)
{
    float4 mn, s;
    mn.x = b * mo.x + cur.x - (mo.x > 1.0f ? 1.0f : 0.0f); s.x = (mn.x - 1.0f) > 0.0f ? 1.0f : 0.0f;
    mn.y = b * mo.y + cur.y - (mo.y > 1.0f ? 1.0f : 0.0f); s.y = (mn.y - 1.0f) > 0.0f ? 1.0f : 0.0f;
    mn.z = b * mo.z + cur.z - (mo.z > 1.0f ? 1.0f : 0.0f); s.z = (mn.z - 1.0f) > 0.0f ? 1.0f : 0.0f;
    mn.w = b * mo.w + cur.w - (mo.w > 1.0f ? 1.0f : 0.0f); s.w = (mn.w - 1.0f) > 0.0f ? 1.0f : 0.0f;
    *sv = s; return mn;
}

// two-level grid barrier (validated round-5)
__device__ __forceinline__ void gbar(unsigned* bar)
{
    __syncthreads();
    if (threadIdx.x == 0) {
        unsigned g = __hip_atomic_load(&bar[0], __ATOMIC_RELAXED, __HIP_MEMORY_SCOPE_AGENT);
        unsigned* gc = &bar[8 + (blockIdx.x & (GRP - 1)) * 32];
        unsigned a = __hip_atomic_fetch_add(gc, 1u, __ATOMIC_ACQ_REL, __HIP_MEMORY_SCOPE_AGENT);
        if (a == GSZ - 1) {
            __hip_atomic_store(gc, 0u, __ATOMIC_RELAXED, __HIP_MEMORY_SCOPE_AGENT);
            unsigned tp = __hip_atomic_fetch_add(&bar[1], 1u, __ATOMIC_ACQ_REL, __HIP_MEMORY_SCOPE_AGENT);
            if (tp == GRP - 1) {
                __hip_atomic_store(&bar[1], 0u, __ATOMIC_RELAXED, __HIP_MEMORY_SCOPE_AGENT);
                __hip_atomic_store(&bar[0], g + 1u, __ATOMIC_RELEASE, __HIP_MEMORY_SCOPE_AGENT);
            }
        }
        while (__hip_atomic_load(&bar[0], __ATOMIC_ACQUIRE, __HIP_MEMORY_SCOPE_AGENT) == g)
            __builtin_amdgcn_s_sleep(2);
    }
    __syncthreads();
}

// 32x32 transpose tile: dst[k][n] = src[n][k]
__device__ __forceinline__ void tr32(float* sm, const float* src, float* dst, int tr, int tc)
{
    const int t = (int)threadIdx.x;
    const int r = t >> 3, c4 = (t & 7) << 2;
    __syncthreads();
    float4 v = ld4(src + (size_t)(tr * 32 + r) * 1024 + tc * 32 + c4);
    sm[r * 33 + c4 + 0] = v.x; sm[r * 33 + c4 + 1] = v.y;
    sm[r * 33 + c4 + 2] = v.z; sm[r * 33 + c4 + 3] = v.w;
    __syncthreads();
    const int kk = t >> 3, nn4 = (t & 7) << 2;
    float4 o;
    o.x = sm[(nn4 + 0) * 33 + kk]; o.y = sm[(nn4 + 1) * 33 + kk];
    o.z = sm[(nn4 + 2) * 33 + kk]; o.w = sm[(nn4 + 3) * 33 + kk];
    st4(dst + (size_t)(tc * 32 + kk) * 1024 + tr * 32 + nn4, o);
}

// dense 128x128 tile of x_t @ W1^T, K=512, k-chunk 8 (LDS 8448 B), k-ascending chain
__device__ __forceinline__ void xw_tile(float* sm, const float* xA, const float* W1,
                                        float* out, int tm, int tn)
{
    float* As = sm;            // [8][132]
    float* Bs = sm + 1056;     // [8][132]
    const int t = (int)threadIdx.x;
    const int ar = t >> 1;             // 0..127
    const int ak = (t & 1) << 2;       // 0 or 4
    const int r0 = (t >> 4) << 3;
    const int c0 = (t & 15) << 3;
    const float* Ab = xA + (size_t)(tm * 128) * 51200;
    const float* Bb = W1 + (size_t)(tn * 128) * 512;
    float4 pa = ld4(Ab + (size_t)ar * 51200 + ak);
    float4 pb = ld4(Bb + (size_t)ar * 512 + ak);
    float acc[8][8] = {};
    for (int c = 0; c < 64; ++c) {
        __syncthreads();
        As[(ak + 0) * 132 + ar] = pa.x; As[(ak + 1) * 132 + ar] = pa.y;
        As[(ak + 2) * 132 + ar] = pa.z; As[(ak + 3) * 132 + ar] = pa.w;
        Bs[(ak + 0) * 132 + ar] = pb.x; Bs[(ak + 1) * 132 + ar] = pb.y;
        Bs[(ak + 2) * 132 + ar] = pb.z; Bs[(ak + 3) * 132 + ar] = pb.w;
        __syncthreads();
        if (c + 1 < 64) {
            const int ko = (c + 1) * 8;
            pa = ld4(Ab + (size_t)ar * 51200 + ko + ak);
            pb = ld4(Bb + (size_t)ar * 512 + ko + ak);
        }
        #pragma unroll
        for (int k = 0; k < 8; ++k) {
            float4 a0 = ld4(&As[k * 132 + r0]);
            float4 a1 = ld4(&As[k * 132 + r0 + 4]);
            float4 b0 = ld4(&Bs[k * 132 + c0]);
            float4 b1 = ld4(&Bs[k * 132 + c0 + 4]);
            float av[8] = {a0.x, a0.y, a0.z, a0.w, a1.x, a1.y, a1.z, a1.w};
            float bv[8] = {b0.x, b0.y, b0.z, b0.w, b1.x, b1.y, b1.z, b1.w};
            #pragma unroll
            for (int i = 0; i < 8; ++i)
                #pragma unroll
                for (int j = 0; j < 8; ++j)
                    acc[i][j] = fmaf(av[i], bv[j], acc[i][j]);
        }
    }
    #pragma unroll
    for (int i = 0; i < 8; ++i) {
        float* row = out + (size_t)(tm * 128 + r0 + i) * 1024 + tn * 128 + c0;
        st4(row,     make_float4(acc[i][0], acc[i][1], acc[i][2], acc[i][3]));
        st4(row + 4, make_float4(acc[i][4], acc[i][5], acc[i][6], acc[i][7]));
    }
}

// 4 concurrent k-ascending chains, depth-2 prefetch; per-chain sums bitwise
// identical to sequential accumulation (round-5 validated chain content).
__device__ __forceinline__ void gather4(const unsigned short* lst,
    const unsigned* pos, const float* Wt, int n4, float4 c[4])
{
    unsigned j[4], e[4];
    float4 pa[4], pb[4];
    #pragma unroll
    for (int q = 0; q < 4; ++q) {
        j[q] = pos[q]; e[q] = pos[q + 1];
        c[q] = make_float4(0.f, 0.f, 0.f, 0.f);
        if (j[q] < e[q])     pa[q] = ld4(Wt + (size_t)lst[j[q]] * 1024 + n4);
        if (j[q] + 1 < e[q]) pb[q] = ld4(Wt + (size_t)lst[j[q] + 1] * 1024 + n4);
    }
    for (;;) {
        bool any = false;
        #pragma unroll
        for (int q = 0; q < 4; ++q) {
            if (j[q] < e[q]) {
                float4 v = pa[q];
                pa[q] = pb[q];
                if (j[q] + 2 < e[q]) pb[q] = ld4(Wt + (size_t)lst[j[q] + 2] * 1024 + n4);
                c[q].x += v.x; c[q].y += v.y; c[q].z += v.z; c[q].w += v.w;
                ++j[q];
                any = any || (j[q] < e[q]);
            }
        }
        if (!any) break;
    }
}

// wave-0 compaction: sorted nonzero indices + per-128-window counts (validated)
__device__ __forceinline__ void build_list(const float* s_spk,
    unsigned short* gidx, unsigned* gcnt)
{
    const int l = (int)threadIdx.x;
    unsigned tot = 0, prev = 0;
    #pragma unroll
    for (int i = 0; i < 16; ++i) {
        float s = s_spk[i * 64 + l];
        unsigned long long m = __ballot(s != 0.0f);
        unsigned off = (unsigned)__popcll(m & ((1ull << l) - 1ull));
        if (s != 0.0f) gidx[tot + off] = (unsigned short)(i * 64 + l);
        tot += (unsigned)__popcll(m);
        if (i & 1) { if (l == 0) gcnt[i >> 1] = tot - prev; prev = tot; }
    }
}

// L1 gather: row r, half h -> window-chains 4h..4h+3, each to its own P1 plane
__device__ __forceinline__ void l1_gather(float* sm, const Ptrs& p, int r, int h, int tau)
{
    const int t = (int)threadIdx.x, n4 = t << 2;
    const int pp = 1 - (tau & 1);
    const unsigned* cw = p.cnt1 + ((size_t)pp * 256 + r) * 8;
    unsigned pos[9];
    pos[0] = 0;
    #pragma unroll
    for (int w = 0; w < 8; ++w) pos[w + 1] = pos[w] + cw[w];
    unsigned* sl = (unsigned*)(sm + 1024);
    const unsigned* gl = (const unsigned*)(p.idx1 + ((size_t)pp * 256 + r) * 1024);
    for (unsigned i = t; i < ((pos[8] + 1) >> 1); i += 256) sl[i] = gl[i];
    __syncthreads();
    unsigned cpos[5];
    #pragma unroll
    for (int q = 0; q <= 4; ++q) cpos[q] = pos[4 * h + q];
    float4 c[4];
    gather4((const unsigned short*)sl, cpos, p.w1rt, n4, c);
    #pragma unroll
    for (int q = 0; q < 4; ++q)
        st4(p.P1 + (size_t)(4 * h + q) * S_ELE + (size_t)r * 1024 + n4, c[q]);
}

// L2 gather: row r, half h (0: W2 chains from list1, 1: W2r chains from list2)
// writes S = c_lo + c_hi to P2 plane h  (validated grouping)
__device__ __forceinline__ void l2_gather(float* sm, const Ptrs& p, int r, int h, int step)
{
    const int t = (int)threadIdx.x, n4 = t << 2;
    const int par = h ? (1 - (step & 1)) : (step & 1);
    const unsigned* cc = (h ? p.cnt2 : p.cnt1) + ((size_t)par * 256 + r) * 8;
    unsigned nlo = cc[0] + cc[1] + cc[2] + cc[3];
    unsigned tot = nlo + cc[4] + cc[5] + cc[6] + cc[7];
    unsigned* sl = (unsigned*)(sm + 1024);
    const unsigned* gl = (const unsigned*)((h ? p.idx2 : p.idx1) + ((size_t)par * 256 + r) * 1024);
    for (unsigned i = t; i < ((tot + 1) >> 1); i += 256) sl[i] = gl[i];
    __syncthreads();
    unsigned cpos[5] = {0, nlo, tot, tot, tot};
    float4 c[4];
    gather4((const unsigned short*)sl, cpos, h ? p.w2rt : p.w2t, n4, c);
    float4 s;
    s.x = c[0].x + c[1].x; s.y = c[0].y + c[1].y;
    s.z = c[0].z + c[1].z; s.w = c[0].w + c[1].w;
    st4(p.P2 + (size_t)h * S_ELE + (size_t)r * 1024 + n4, s);
}

// update layer 1: cur = xw + P0..P7 sequential (round-2/4 validated order)
__device__ __forceinline__ void upd1_row(float* sm, const Ptrs& p, int r, int tau)
{
    const int t = (int)threadIdx.x, n4 = t << 2;
    const size_t base = (size_t)r * 1024 + n4;
    const int slot = tau % p.t_ch;
    float4 acc = ld4(p.xw + (size_t)slot * S_ELE + base);
    #pragma unroll
    for (int w = 0; w < 8; ++w) {
        float4 q = ld4(p.P1 + (size_t)w * S_ELE + base);
        acc.x += q.x; acc.y += q.y; acc.z += q.z; acc.w += q.w;
    }
    const float bb = clip01(*p.b1);
    float4 mo = ld4(p.mem1 + base);
    float4 sv; float4 mn = memup(mo, acc, bb, &sv);
    st4(p.mem1 + base, mn);
    st4(p.spk1_rec + (size_t)tau * S_ELE + base, sv);
    sm[n4 + 0] = sv.x; sm[n4 + 1] = sv.y; sm[n4 + 2] = sv.z; sm[n4 + 3] = sv.w;
    __syncthreads();
    if (t < 64) build_list(sm, p.idx1 + ((size_t)(tau & 1) * 256 + r) * 1024,
                           p.cnt1 + ((size_t)(tau & 1) * 256 + r) * 8);
}

// update layer 2 + readout: cur = S_A + S_B (validated grouping)
__device__ __forceinline__ void upd2_row(float* sm, const Ptrs& p, int r, int step)
{
    const int t = (int)threadIdx.x, n4 = t << 2;
    const size_t base = (size_t)r * 1024 + n4;
    float4 sa = ld4(p.P2 + base);
    float4 sb = ld4(p.P2 + (size_t)S_ELE + base);
    float4 cur = make_float4(sa.x + sb.x, sa.y + sb.y, sa.z + sb.z, sa.w + sb.w);
    const float bb = clip01(*p.b2);
    float4 mo = ld4(p.mem2 + base);
    float4 sv; float4 mn = memup(mo, cur, bb, &sv);
    st4(p.mem2 + base, mn);
    sm[n4 + 0] = sv.x; sm[n4 + 1] = sv.y; sm[n4 + 2] = sv.z; sm[n4 + 3] = sv.w;
    __syncthreads();
    if (t < 64) build_list(sm, p.idx2 + ((size_t)(step & 1) * 256 + r) * 1024,
                           p.cnt2 + ((size_t)(step & 1) * 256 + r) * 8);
    const int wave = t >> 6, lane = t & 63;
    const float bo = clip01(*p.bo);
    float v[16];
    #pragma unroll
    for (int i = 0; i < 16; ++i) v[i] = sm[lane + 64 * i];
    float* rec = p.mout_rec + (size_t)step * 2560;
    for (int o = wave; o < 10; o += 4) {
        float sum = 0.0f;
        #pragma unroll
        for (int i = 0; i < 16; ++i)
            sum = fmaf(v[i], p.Wout[o * 1024 + lane + 64 * i], sum);
        #pragma unroll
        for (int off = 32; off > 0; off >>= 1) sum += __shfl_down(sum, off);
        if (lane == 0) {
            const float m = bo * p.memo[r * 10 + o] + sum;
            p.memo[r * 10 + o] = m;
            rec[r * 10 + o] = m;
        }
    }
}

// ---- persistent cooperative kernel: 2 barriers/step ----
__global__ __launch_bounds__(256, 4) void snn_all(Ptrs p)
{
    __shared__ float sm[2176];          // 8704 B
    const int bid = (int)blockIdx.x;

    for (int task = bid; task < 3072; task += NBLK) {
        const float* src = task < 1024 ? p.W1r : (task < 2048 ? p.W2 : p.W2r);
        float* dst = task < 1024 ? p.w1rt : (task < 2048 ? p.w2t : p.w2rt);
        const int id = task & 1023;
        tr32(sm, src, dst, id >> 5, id & 31);
    }
    gbar(p.bar);

    for (int tau = 0; tau <= 100; ++tau) {
        if (tau < 100 && (tau % p.t_ch) == 0) {
            const int ntask = p.t_ch * 16;
            for (int task = bid; task < ntask; task += NBLK) {
                const int tp = task >> 4, tile = task & 15;
                xw_tile(sm, p.x + (size_t)(tau + tp) * 512, p.W1,
                        p.xw + (size_t)tp * S_ELE, tile >> 3, tile & 7);
            }
            gbar(p.bar);
        }
        // phase A: gathers
        if (bid < 512) { if (tau < 100) l1_gather(sm, p, bid >> 1, bid & 1, tau); }
        else           { if (tau >= 1)  l2_gather(sm, p, (bid - 512) >> 1, bid & 1, tau - 1); }
        gbar(p.bar);
        // phase B: updates
        if (bid < 256)      { if (tau < 100) upd1_row(sm, p, bid, tau); }
        else if (bid < 512) { if (tau >= 1)  upd2_row(sm, p, bid - 256, tau - 1); }
        gbar(p.bar);
    }
}

// ---- fallback kernels (kernel boundaries as barriers) ----
__global__ __launch_bounds__(256, 4) void fb_pre(Ptrs p)
{
    __shared__ float sm[2176];
    for (int task = blockIdx.x; task < 3072; task += gridDim.x) {
        const float* src = task < 1024 ? p.W1r : (task < 2048 ? p.W2 : p.W2r);
        float* dst = task < 1024 ? p.w1rt : (task < 2048 ? p.w2t : p.w2rt);
        const int id = task & 1023;
        tr32(sm, src, dst, id >> 5, id & 31);
    }
}

__global__ __launch_bounds__(256, 4) void fb_xw(Ptrs p, int t0)
{
    __shared__ float sm[2176];
    const int task = (int)blockIdx.x;
    const int tp = task >> 4, tile = task & 15;
    xw_tile(sm, p.x + (size_t)(t0 + tp) * 512, p.W1,
            p.xw + (size_t)tp * S_ELE, tile >> 3, tile & 7);
}

__global__ __launch_bounds__(256, 4) void fb_gA(Ptrs p, int tau)
{
    __shared__ float sm[2176];
    const int bid = (int)blockIdx.x;
    if (bid < 512) { if (tau < 100) l1_gather(sm, p, bid >> 1, bid & 1, tau); }
    else           { if (tau >= 1)  l2_gather(sm, p, (bid - 512) >> 1, bid & 1, tau - 1); }
}

__global__ __launch_bounds__(256, 4) void fb_gB(Ptrs p, int tau)
{
    __shared__ float sm[2176];
    const int bid = (int)blockIdx.x;
    if (bid < 256) { if (tau < 100) upd1_row(sm, p, bid, tau); }
    else           { if (tau >= 1)  upd2_row(sm, p, bid - 256, tau - 1); }
}

extern "C" void kernel_launch(void* const* d_in, const int* in_sizes, int n_in,
                              void* d_out, int out_size, void* d_ws, size_t ws_size,
                              hipStream_t stream)
{
    Ptrs p;
    p.x    = (const float*)d_in[0];
    p.W1   = (const float*)d_in[1];
    p.W1r  = (const float*)d_in[2];
    p.W2   = (const float*)d_in[3];
    p.W2r  = (const float*)d_in[4];
    p.Wout = (const float*)d_in[5];
    p.b1   = (const float*)d_in[6];
    p.b2   = (const float*)d_in[7];
    p.bo   = (const float*)d_in[8];

    float* out = (float*)d_out;
    p.spk1_rec = out;
    p.mout_rec = out + (size_t)100 * S_ELE;

    float* w = (float*)d_ws;
    p.mem1 = w;  w += S_ELE;
    p.mem2 = w;  w += S_ELE;
    p.memo = w;  w += 2560;
    p.bar  = (unsigned*)w;  w += 512;
    p.cnt1 = (unsigned*)w;  w += 4096;
    p.cnt2 = (unsigned*)w;  w += 4096;
    p.idx1 = (unsigned short*)w;  w += 262144;
    p.idx2 = (unsigned short*)w;  w += 262144;
    p.w1rt = w;  w += 1048576;
    p.w2t  = w;  w += 1048576;
    p.w2rt = w;  w += 1048576;
    p.P1   = w;  w += 8 * S_ELE;
    p.P2   = w;  w += 2 * S_ELE;
    p.xw   = w;

    const size_t used = (size_t)(w - (float*)d_ws) * sizeof(float);
    int t_ch = 1;
    const int cands[] = {100, 50, 25, 20, 10, 5, 4, 2, 1};
    for (int c : cands)
        if (used + (size_t)c * S_ELE * sizeof(float) <= ws_size) { t_ch = c; break; }
    p.t_ch = t_ch;

    // zero mem1,mem2,memo,bar,cnt1,cnt2 (contiguous)
    hipMemsetAsync(p.mem1, 0,
                   ((size_t)2 * S_ELE + 2560 + 512 + 8192) * sizeof(float), stream);

    int maxb = 0;
    hipError_t qerr = hipOccupancyMaxActiveBlocksPerMultiprocessor(
        &maxb, (const void*)snn_all, 256, 0);
    bool coop = (qerr == hipSuccess && maxb >= 4);

    if (coop) {
        void* args[] = { (void*)&p };
        if (hipLaunchCooperativeKernel((const void*)snn_all, dim3(NBLK), dim3(256),
                                       args, 0, stream) != hipSuccess)
            coop = false;
    }

    if (!coop) {
        hipLaunchKernelGGL(fb_pre, dim3(NBLK), dim3(256), 0, stream, p);
        for (int tau = 0; tau <= 100; ++tau) {
            if (tau < 100 && (tau % t_ch) == 0)
                hipLaunchKernelGGL(fb_xw, dim3(t_ch * 16), dim3(256), 0, stream, p, tau);
            hipLaunchKernelGGL(fb_gA, dim3(NBLK), dim3(256), 0, stream, p, tau);
            hipLaunchKernelGGL(fb_gB, dim3(512), dim3(256), 0, stream, p, tau);
        }
    }
}

// Round 8
// 4526.506 us; speedup vs baseline: 9.9465x; 1.1648x over previous
//
#include <hip/hip_runtime.h>

#define S_ELE (256 * 1024)   // one [B=256, H=1024] plane (floats)
#define NBLK 512
#define GRP  8
#define GSZ  (NBLK / GRP)

typedef float f32x4 __attribute__((ext_vector_type(4)));

struct Ptrs {
    const float *x, *W1, *W1r, *W2, *W2r, *Wout;
    const float *b1, *b2, *bo;
    float *spk1_rec, *mout_rec;
    float *mem1, *mem2, *memo;
    float *w1rt, *w2t, *w2rt, *xw, *S2;
    unsigned *bar, *cnt1, *cnt2;
    unsigned short *idx1, *idx2;
    int t_ch;
};

__device__ __forceinline__ float clip01(float b) { return fminf(fmaxf(b, 0.0f), 1.0f); }
__device__ __forceinline__ float4 ld4(const float* p) { return *reinterpret_cast<const float4*>(p); }
__device__ __forceinline__ void   st4(float* p, float4 v) { *reinterpret_cast<float4*>(p) = v; }
__device__ __forceinline__ void   st4nt(float* p, float4 v)
{
    f32x4 n = { v.x, v.y, v.z, v.w };
    __builtin_nontemporal_store(n, reinterpret_cast<f32x4*>(p));
}

// validated membrane update (round-2 arithmetic)
__device__ __forceinline__ float4 memup(float4 mo, float4 cur, float b, float4* sv)
{
    float4 mn, s;
    mn.x = b * mo.x + cur.x - (mo.x > 1.0f ? 1.0f : 0.0f); s.x = (mn.x - 1.0f) > 0.0f ? 1.0f : 0.0f;
    mn.y = b * mo.y + cur.y - (mo.y > 1.0f ? 1.0f : 0.0f); s.y = (mn.y - 1.0f) > 0.0f ? 1.0f : 0.0f;
    mn.z = b * mo.z + cur.z - (mo.z > 1.0f ? 1.0f : 0.0f); s.z = (mn.z - 1.0f) > 0.0f ? 1.0f : 0.0f;
    mn.w = b * mo.w + cur.w - (mo.w > 1.0f ? 1.0f : 0.0f); s.w = (mn.w - 1.0f) > 0.0f ? 1.0f : 0.0f;
    *sv = s; return mn;
}

// two-level grid barrier (validated round-5/6)
__device__ __forceinline__ void gbar(unsigned* bar)
{
    __syncthreads();
    if (threadIdx.x == 0) {
        unsigned g = __hip_atomic_load(&bar[0], __ATOMIC_RELAXED, __HIP_MEMORY_SCOPE_AGENT);
        unsigned* gc = &bar[8 + (blockIdx.x & (GRP - 1)) * 32];
        unsigned a = __hip_atomic_fetch_add(gc, 1u, __ATOMIC_ACQ_REL, __HIP_MEMORY_SCOPE_AGENT);
        if (a == GSZ - 1) {
            __hip_atomic_store(gc, 0u, __ATOMIC_RELAXED, __HIP_MEMORY_SCOPE_AGENT);
            unsigned tp = __hip_atomic_fetch_add(&bar[1], 1u, __ATOMIC_ACQ_REL, __HIP_MEMORY_SCOPE_AGENT);
            if (tp == GRP - 1) {
                __hip_atomic_store(&bar[1], 0u, __ATOMIC_RELAXED, __HIP_MEMORY_SCOPE_AGENT);
                __hip_atomic_store(&bar[0], g + 1u, __ATOMIC_RELEASE, __HIP_MEMORY_SCOPE_AGENT);
            }
        }
        while (__hip_atomic_load(&bar[0], __ATOMIC_ACQUIRE, __HIP_MEMORY_SCOPE_AGENT) == g)
            __builtin_amdgcn_s_sleep(2);
    }
    __syncthreads();
}

// 32x32 transpose tile: dst[k][n] = src[n][k]
__device__ __forceinline__ void tr32(float* sm, const float* src, float* dst, int tr, int tc)
{
    const int t = (int)threadIdx.x;
    const int r = t >> 3, c4 = (t & 7) << 2;
    __syncthreads();
    float4 v = ld4(src + (size_t)(tr * 32 + r) * 1024 + tc * 32 + c4);
    sm[r * 33 + c4 + 0] = v.x; sm[r * 33 + c4 + 1] = v.y;
    sm[r * 33 + c4 + 2] = v.z; sm[r * 33 + c4 + 3] = v.w;
    __syncthreads();
    const int kk = t >> 3, nn4 = (t & 7) << 2;
    float4 o;
    o.x = sm[(nn4 + 0) * 33 + kk]; o.y = sm[(nn4 + 1) * 33 + kk];
    o.z = sm[(nn4 + 2) * 33 + kk]; o.w = sm[(nn4 + 3) * 33 + kk];
    st4(dst + (size_t)(tc * 32 + kk) * 1024 + tr * 32 + nn4, o);
}

// dense 128x128 tile of x_t @ W1^T, K=512, k-chunk 8, k-ascending chain (validated)
__device__ __forceinline__ void xw_tile(float* sm, const float* xA, const float* W1,
                                        float* out, int tm, int tn)
{
    float* As = sm;            // [8][132]
    float* Bs = sm + 1056;     // [8][132]
    const int t = (int)threadIdx.x;
    const int ar = t >> 1;
    const int ak = (t & 1) << 2;
    const int r0 = (t >> 4) << 3;
    const int c0 = (t & 15) << 3;
    const float* Ab = xA + (size_t)(tm * 128) * 51200;
    const float* Bb = W1 + (size_t)(tn * 128) * 512;
    float4 pa = ld4(Ab + (size_t)ar * 51200 + ak);
    float4 pb = ld4(Bb + (size_t)ar * 512 + ak);
    float acc[8][8] = {};
    for (int c = 0; c < 64; ++c) {
        __syncthreads();
        As[(ak + 0) * 132 + ar] = pa.x; As[(ak + 1) * 132 + ar] = pa.y;
        As[(ak + 2) * 132 + ar] = pa.z; As[(ak + 3) * 132 + ar] = pa.w;
        Bs[(ak + 0) * 132 + ar] = pb.x; Bs[(ak + 1) * 132 + ar] = pb.y;
        Bs[(ak + 2) * 132 + ar] = pb.z; Bs[(ak + 3) * 132 + ar] = pb.w;
        __syncthreads();
        if (c + 1 < 64) {
            const int ko = (c + 1) * 8;
            pa = ld4(Ab + (size_t)ar * 51200 + ko + ak);
            pb = ld4(Bb + (size_t)ar * 512 + ko + ak);
        }
        #pragma unroll
        for (int k = 0; k < 8; ++k) {
            float4 a0 = ld4(&As[k * 132 + r0]);
            float4 a1 = ld4(&As[k * 132 + r0 + 4]);
            float4 b0 = ld4(&Bs[k * 132 + c0]);
            float4 b1 = ld4(&Bs[k * 132 + c0 + 4]);
            float av[8] = {a0.x, a0.y, a0.z, a0.w, a1.x, a1.y, a1.z, a1.w};
            float bv[8] = {b0.x, b0.y, b0.z, b0.w, b1.x, b1.y, b1.z, b1.w};
            #pragma unroll
            for (int i = 0; i < 8; ++i)
                #pragma unroll
                for (int j = 0; j < 8; ++j)
                    acc[i][j] = fmaf(av[i], bv[j], acc[i][j]);
        }
    }
    #pragma unroll
    for (int i = 0; i < 8; ++i) {
        float* row = out + (size_t)(tm * 128 + r0 + i) * 1024 + tn * 128 + c0;
        st4(row,     make_float4(acc[i][0], acc[i][1], acc[i][2], acc[i][3]));
        st4(row + 4, make_float4(acc[i][4], acc[i][5], acc[i][6], acc[i][7]));
    }
}

// NC concurrent k-ascending chains, depth-2 prefetch; per-chain arithmetic
// identical to round-6 gather4 (validated). Full unroll keeps arrays in regs.
template <int NC>
__device__ __forceinline__ void gatherN(const unsigned short* const lp[],
    const unsigned st[], const unsigned en[], const float* Wt, int n4, float4 c[])
{
    unsigned j[NC], e[NC];
    float4 pa[NC], pb[NC];
    #pragma unroll
    for (int q = 0; q < NC; ++q) {
        j[q] = st[q]; e[q] = en[q];
        c[q] = make_float4(0.f, 0.f, 0.f, 0.f);
        if (j[q] < e[q])     pa[q] = ld4(Wt + (size_t)lp[q][j[q]] * 1024 + n4);
        if (j[q] + 1 < e[q]) pb[q] = ld4(Wt + (size_t)lp[q][j[q] + 1] * 1024 + n4);
    }
    for (;;) {
        bool any = false;
        #pragma unroll
        for (int q = 0; q < NC; ++q) {
            if (j[q] < e[q]) {
                float4 v = pa[q];
                pa[q] = pb[q];
                if (j[q] + 2 < e[q]) pb[q] = ld4(Wt + (size_t)lp[q][j[q] + 2] * 1024 + n4);
                c[q].x += v.x; c[q].y += v.y; c[q].z += v.z; c[q].w += v.w;
                ++j[q];
                any = any || (j[q] < e[q]);
            }
        }
        if (!any) break;
    }
}

// wave-0 compaction: sorted nonzero indices + per-128-window counts (validated)
__device__ __forceinline__ void build_list(const float* s_spk,
    unsigned short* gidx, unsigned* gcnt)
{
    const int l = (int)threadIdx.x;
    unsigned tot = 0, prev = 0;
    #pragma unroll
    for (int i = 0; i < 16; ++i) {
        float s = s_spk[i * 64 + l];
        unsigned long long m = __ballot(s != 0.0f);
        unsigned off = (unsigned)__popcll(m & ((1ull << l) - 1ull));
        if (s != 0.0f) gidx[tot + off] = (unsigned short)(i * 64 + l);
        tot += (unsigned)__popcll(m);
        if (i & 1) { if (l == 0) gcnt[i >> 1] = tot - prev; prev = tot; }
    }
}

// fused L1 row: 8 concurrent window-chains, acc = xw + c0 + ... + c7
// (bitwise identical to round-6 l1_gather + upd1_row), update, list build.
__device__ __forceinline__ void l1_full(float* sm, const Ptrs& p, int r, int tau)
{
    const int t = (int)threadIdx.x, n4 = t << 2;
    const int pp = 1 - (tau & 1);
    const unsigned* cw = p.cnt1 + ((size_t)pp * 256 + r) * 8;
    unsigned pos[9];
    pos[0] = 0;
    #pragma unroll
    for (int w = 0; w < 8; ++w) pos[w + 1] = pos[w] + cw[w];
    unsigned* sl = (unsigned*)(sm + 1024);
    const unsigned* gl = (const unsigned*)(p.idx1 + ((size_t)pp * 256 + r) * 1024);
    for (unsigned i = t; i < ((pos[8] + 1) >> 1); i += 256) sl[i] = gl[i];
    __syncthreads();
    const unsigned short* sl16 = (const unsigned short*)sl;
    const unsigned short* lp[8];
    unsigned st[8], en[8];
    #pragma unroll
    for (int q = 0; q < 8; ++q) { lp[q] = sl16; st[q] = pos[q]; en[q] = pos[q + 1]; }
    float4 c[8];
    gatherN<8>(lp, st, en, p.w1rt, n4, c);

    const size_t base = (size_t)r * 1024 + n4;
    const int slot = tau % p.t_ch;
    float4 acc = ld4(p.xw + (size_t)slot * S_ELE + base);
    #pragma unroll
    for (int w = 0; w < 8; ++w) {
        acc.x += c[w].x; acc.y += c[w].y; acc.z += c[w].z; acc.w += c[w].w;
    }
    const float bb = clip01(*p.b1);
    float4 mo = ld4(p.mem1 + base);
    float4 sv; float4 mn = memup(mo, acc, bb, &sv);
    st4(p.mem1 + base, mn);
    st4nt(p.spk1_rec + (size_t)tau * S_ELE + base, sv);
    sm[n4 + 0] = sv.x; sm[n4 + 1] = sv.y; sm[n4 + 2] = sv.z; sm[n4 + 3] = sv.w;
    __syncthreads();
    if (t < 64) build_list(sm, p.idx1 + ((size_t)(tau & 1) * 256 + r) * 1024,
                           p.cnt1 + ((size_t)(tau & 1) * 256 + r) * 8);
}

// L2 gather, 2 rows per block, 4 concurrent chains; per row S = c_lo + c_hi
// (validated round-6 grouping). rsel: 0 = W2/list1, 1 = W2r/list2.
__device__ __forceinline__ void l2g(float* sm, const Ptrs& p, int idx, int rsel, int step)
{
    const int t = (int)threadIdx.x, n4 = t << 2;
    const int r0 = idx * 2, r1 = r0 + 1;
    const int par = rsel ? (1 - (step & 1)) : (step & 1);
    const unsigned* cbase = (rsel ? p.cnt2 : p.cnt1) + (size_t)par * 256 * 8;
    const unsigned short* ibase = (rsel ? p.idx2 : p.idx1) + (size_t)par * 256 * 1024;
    const unsigned* cA = cbase + (size_t)r0 * 8;
    const unsigned* cB = cbase + (size_t)r1 * 8;
    unsigned nlo0 = cA[0] + cA[1] + cA[2] + cA[3];
    unsigned tot0 = nlo0 + cA[4] + cA[5] + cA[6] + cA[7];
    unsigned nlo1 = cB[0] + cB[1] + cB[2] + cB[3];
    unsigned tot1 = nlo1 + cB[4] + cB[5] + cB[6] + cB[7];
    unsigned* sl0 = (unsigned*)(sm + 1024);
    unsigned* sl1 = (unsigned*)(sm + 1536);
    const unsigned* g0 = (const unsigned*)(ibase + (size_t)r0 * 1024);
    const unsigned* g1 = (const unsigned*)(ibase + (size_t)r1 * 1024);
    for (unsigned i = t; i < ((tot0 + 1) >> 1); i += 256) sl0[i] = g0[i];
    for (unsigned i = t; i < ((tot1 + 1) >> 1); i += 256) sl1[i] = g1[i];
    __syncthreads();
    const unsigned short* lp[4] = {(const unsigned short*)sl0, (const unsigned short*)sl0,
                                   (const unsigned short*)sl1, (const unsigned short*)sl1};
    unsigned st[4] = {0, nlo0, 0, nlo1};
    unsigned en[4] = {nlo0, tot0, nlo1, tot1};
    float4 c[4];
    gatherN<4>(lp, st, en, rsel ? p.w2rt : p.w2t, n4, c);
    float* Sp = p.S2 + (size_t)rsel * S_ELE;
    st4(Sp + (size_t)r0 * 1024 + n4,
        make_float4(c[0].x + c[1].x, c[0].y + c[1].y, c[0].z + c[1].z, c[0].w + c[1].w));
    st4(Sp + (size_t)r1 * 1024 + n4,
        make_float4(c[2].x + c[3].x, c[2].y + c[3].y, c[2].z + c[3].z, c[2].w + c[3].w));
}

// update layer 2 + readout: cur = S_A + S_B (validated grouping)
__device__ __forceinline__ void upd2_row(float* sm, const Ptrs& p, int r, int step)
{
    const int t = (int)threadIdx.x, n4 = t << 2;
    const size_t base = (size_t)r * 1024 + n4;
    float4 sa = ld4(p.S2 + base);
    float4 sb = ld4(p.S2 + (size_t)S_ELE + base);
    float4 cur = make_float4(sa.x + sb.x, sa.y + sb.y, sa.z + sb.z, sa.w + sb.w);
    const float bb = clip01(*p.b2);
    float4 mo = ld4(p.mem2 + base);
    float4 sv; float4 mn = memup(mo, cur, bb, &sv);
    st4(p.mem2 + base, mn);
    sm[n4 + 0] = sv.x; sm[n4 + 1] = sv.y; sm[n4 + 2] = sv.z; sm[n4 + 3] = sv.w;
    __syncthreads();
    if (t < 64) build_list(sm, p.idx2 + ((size_t)(step & 1) * 256 + r) * 1024,
                           p.cnt2 + ((size_t)(step & 1) * 256 + r) * 8);
    const int wave = t >> 6, lane = t & 63;
    const float bo = clip01(*p.bo);
    float v[16];
    #pragma unroll
    for (int i = 0; i < 16; ++i) v[i] = sm[lane + 64 * i];
    float* rec = p.mout_rec + (size_t)step * 2560;
    for (int o = wave; o < 10; o += 4) {
        float sum = 0.0f;
        #pragma unroll
        for (int i = 0; i < 16; ++i)
            sum = fmaf(v[i], p.Wout[o * 1024 + lane + 64 * i], sum);
        #pragma unroll
        for (int off = 32; off > 0; off >>= 1) sum += __shfl_down(sum, off);
        if (lane == 0) {
            const float m = bo * p.memo[r * 10 + o] + sum;
            p.memo[r * 10 + o] = m;
            __builtin_nontemporal_store(m, &rec[r * 10 + o]);
        }
    }
}

// ---- persistent cooperative kernel, XCD-partitioned roles via bid&7 ----
// XCD 0-3: L1 rows (w1rt resident); XCD 4-5: W2 chains; XCD 6-7: W2r chains.
__global__ __launch_bounds__(256, 2) void snn_all(Ptrs p)
{
    __shared__ float sm[2176];          // 8704 B
    const int bid = (int)blockIdx.x;
    const int x = bid & 7, g = bid >> 3;

    for (int task = bid; task < 3072; task += NBLK) {
        const float* src = task < 1024 ? p.W1r : (task < 2048 ? p.W2 : p.W2r);
        float* dst = task < 1024 ? p.w1rt : (task < 2048 ? p.w2t : p.w2rt);
        const int id = task & 1023;
        tr32(sm, src, dst, id >> 5, id & 31);
    }
    gbar(p.bar);

    for (int tau = 0; tau <= 100; ++tau) {
        if (tau < 100 && (tau % p.t_ch) == 0) {
            const int ntask = p.t_ch * 16;
            for (int task = bid; task < ntask; task += NBLK) {
                const int tp = task >> 4, tile = task & 15;
                xw_tile(sm, p.x + (size_t)(tau + tp) * 512, p.W1,
                        p.xw + (size_t)tp * S_ELE, tile >> 3, tile & 7);
            }
            gbar(p.bar);
        }
        // phase 1: L1(tau) fused  ||  L2 gathers for step tau-1
        if (x < 4)      { if (tau < 100) l1_full(sm, p, g * 4 + x, tau); }
        else if (x < 6) { if (tau >= 1)  l2g(sm, p, g * 2 + (x - 4), 0, tau - 1); }
        else            { if (tau >= 1)  l2g(sm, p, g * 2 + (x - 6), 1, tau - 1); }
        gbar(p.bar);
        // phase 2: upd2 + readout for step tau-1 (on XCDs 4-7)
        if (x >= 4 && tau >= 1) upd2_row(sm, p, g * 4 + (x - 4), tau - 1);
        gbar(p.bar);
    }
}

// ---- fallback kernels (kernel boundaries as barriers) ----
__global__ __launch_bounds__(256, 2) void fb_pre(Ptrs p)
{
    __shared__ float sm[2176];
    for (int task = blockIdx.x; task < 3072; task += gridDim.x) {
        const float* src = task < 1024 ? p.W1r : (task < 2048 ? p.W2 : p.W2r);
        float* dst = task < 1024 ? p.w1rt : (task < 2048 ? p.w2t : p.w2rt);
        const int id = task & 1023;
        tr32(sm, src, dst, id >> 5, id & 31);
    }
}

__global__ __launch_bounds__(256, 2) void fb_xw(Ptrs p, int t0)
{
    __shared__ float sm[2176];
    const int task = (int)blockIdx.x;
    const int tp = task >> 4, tile = task & 15;
    xw_tile(sm, p.x + (size_t)(t0 + tp) * 512, p.W1,
            p.xw + (size_t)tp * S_ELE, tile >> 3, tile & 7);
}

__global__ __launch_bounds__(256, 2) void fb_p1(Ptrs p, int tau)
{
    __shared__ float sm[2176];
    const int bid = (int)blockIdx.x;
    const int x = bid & 7, g = bid >> 3;
    if (x < 4)      { if (tau < 100) l1_full(sm, p, g * 4 + x, tau); }
    else if (x < 6) { if (tau >= 1)  l2g(sm, p, g * 2 + (x - 4), 0, tau - 1); }
    else            { if (tau >= 1)  l2g(sm, p, g * 2 + (x - 6), 1, tau - 1); }
}

__global__ __launch_bounds__(256, 2) void fb_p2(Ptrs p, int tau)
{
    __shared__ float sm[2176];
    if (tau >= 1) upd2_row(sm, p, (int)blockIdx.x, tau - 1);
}

extern "C" void kernel_launch(void* const* d_in, const int* in_sizes, int n_in,
                              void* d_out, int out_size, void* d_ws, size_t ws_size,
                              hipStream_t stream)
{
    Ptrs p;
    p.x    = (const float*)d_in[0];
    p.W1   = (const float*)d_in[1];
    p.W1r  = (const float*)d_in[2];
    p.W2   = (const float*)d_in[3];
    p.W2r  = (const float*)d_in[4];
    p.Wout = (const float*)d_in[5];
    p.b1   = (const float*)d_in[6];
    p.b2   = (const float*)d_in[7];
    p.bo   = (const float*)d_in[8];

    float* out = (float*)d_out;
    p.spk1_rec = out;
    p.mout_rec = out + (size_t)100 * S_ELE;

    float* w = (float*)d_ws;
    p.mem1 = w;  w += S_ELE;
    p.mem2 = w;  w += S_ELE;
    p.memo = w;  w += 2560;
    p.bar  = (unsigned*)w;  w += 512;
    p.cnt1 = (unsigned*)w;  w += 4096;
    p.cnt2 = (unsigned*)w;  w += 4096;
    p.idx1 = (unsigned short*)w;  w += 262144;
    p.idx2 = (unsigned short*)w;  w += 262144;
    p.w1rt = w;  w += 1048576;
    p.w2t  = w;  w += 1048576;
    p.w2rt = w;  w += 1048576;
    p.S2   = w;  w += 2 * S_ELE;
    p.xw   = w;

    const size_t used = (size_t)(w - (float*)d_ws) * sizeof(float);
    int t_ch = 1;
    const int cands[] = {100, 50, 25, 20, 10, 5, 4, 2, 1};
    for (int c : cands)
        if (used + (size_t)c * S_ELE * sizeof(float) <= ws_size) { t_ch = c; break; }
    p.t_ch = t_ch;

    // zero mem1, mem2, memo, bar, cnt1, cnt2 (contiguous)
    (void)hipMemsetAsync(p.mem1, 0,
                   ((size_t)2 * S_ELE + 2560 + 512 + 8192) * sizeof(float), stream);

    int maxb = 0;
    hipError_t qerr = hipOccupancyMaxActiveBlocksPerMultiprocessor(
        &maxb, (const void*)snn_all, 256, 0);
    bool coop = (qerr == hipSuccess && maxb >= 2);

    if (coop) {
        void* args[] = { (void*)&p };
        if (hipLaunchCooperativeKernel((const void*)snn_all, dim3(NBLK), dim3(256),
                                       args, 0, stream) != hipSuccess)
            coop = false;
    }

    if (!coop) {
        hipLaunchKernelGGL(fb_pre, dim3(NBLK), dim3(256), 0, stream, p);
        for (int tau = 0; tau <= 100; ++tau) {
            if (tau < 100 && (tau % t_ch) == 0)
                hipLaunchKernelGGL(fb_xw, dim3(t_ch * 16), dim3(256), 0, stream, p, tau);
            hipLaunchKernelGGL(fb_p1, dim3(NBLK), dim3(256), 0, stream, p, tau);
            hipLaunchKernelGGL(fb_p2, dim3(256), dim3(256), 0, stream, p, tau);
        }
    }
}